// Round 1
// baseline (429.251 us; speedup 1.0000x reference)
//
#include <hip/hip_runtime.h>

// Problem constants (from reference): x is (B=16, C4=256, H=128, W=128) f32,
// out is (B=16, C=64, 2H=256, 2W=256) f32.
// out[b,c,2i+0,2j+0] = 0.5*(a - bb - cc + d)   (h00)
// out[b,c,2i+0,2j+1] = 0.5*(a + bb - cc - d)   (h01)
// out[b,c,2i+1,2j+0] = 0.5*(a - bb + cc - d)   (h10)
// out[b,c,2i+1,2j+1] = 0.5*(a + bb + cc + d)   (h11)
// where a=x[b,c], bb=x[b,c+64], cc=x[b,c+128], d=x[b,c+192].

#define IWT_B 16
#define IWT_C 64
#define IWT_H 128
#define IWT_W 128

__global__ __launch_bounds__(256) void IWT_kernel(const float* __restrict__ x,
                                                  float* __restrict__ out) {
    // One thread per (b, c, i, jv) with jv indexing a 4-wide column chunk.
    // W/4 = 32 chunks per row.
    const unsigned tid = blockIdx.x * 256u + threadIdx.x;
    // total threads = B*C*H*(W/4) = 16*64*128*32 = 4194304
    const int jv = tid & 31;          // W/4 - 1
    const int i  = (tid >> 5) & 127;  // H - 1
    const int c  = (tid >> 12) & 63;  // C - 1
    const int b  = tid >> 18;

    const long long chanStride = (long long)IWT_H * IWT_W;  // 16384
    const long long inBase =
        (((long long)b * 256 + c) * IWT_H + i) * IWT_W + (jv << 2);

    const float4 a  = *(const float4*)(x + inBase);
    const float4 bb = *(const float4*)(x + inBase + 64  * chanStride);
    const float4 cc = *(const float4*)(x + inBase + 128 * chanStride);
    const float4 d  = *(const float4*)(x + inBase + 192 * chanStride);

    // Per-element Haar recombine.
    float h00[4], h01[4], h10[4], h11[4];
    const float av[4]  = {a.x, a.y, a.z, a.w};
    const float bv[4]  = {bb.x, bb.y, bb.z, bb.w};
    const float cv[4]  = {cc.x, cc.y, cc.z, cc.w};
    const float dv[4]  = {d.x, d.y, d.z, d.w};
#pragma unroll
    for (int e = 0; e < 4; ++e) {
        h00[e] = 0.5f * (av[e] - bv[e] - cv[e] + dv[e]);
        h01[e] = 0.5f * (av[e] + bv[e] - cv[e] - dv[e]);
        h10[e] = 0.5f * (av[e] - bv[e] + cv[e] - dv[e]);
        h11[e] = 0.5f * (av[e] + bv[e] + cv[e] + dv[e]);
    }

    // Output: (B, 64, 256, 256). Rows 2i and 2i+1, cols 8*jv .. 8*jv+7.
    const long long outRow0 =
        (((long long)b * IWT_C + c) * (2 * IWT_H) + 2 * i) * (2 * IWT_W) + (jv << 3);
    const long long outRow1 = outRow0 + 2 * IWT_W;

    float4 r0a = make_float4(h00[0], h01[0], h00[1], h01[1]);
    float4 r0b = make_float4(h00[2], h01[2], h00[3], h01[3]);
    float4 r1a = make_float4(h10[0], h11[0], h10[1], h11[1]);
    float4 r1b = make_float4(h10[2], h11[2], h10[3], h11[3]);

    *(float4*)(out + outRow0)     = r0a;
    *(float4*)(out + outRow0 + 4) = r0b;
    *(float4*)(out + outRow1)     = r1a;
    *(float4*)(out + outRow1 + 4) = r1b;
}

extern "C" void kernel_launch(void* const* d_in, const int* in_sizes, int n_in,
                              void* d_out, int out_size, void* d_ws, size_t ws_size,
                              hipStream_t stream) {
    const float* x = (const float*)d_in[0];
    float* out = (float*)d_out;
    // total threads = 4194304; 256/block -> 16384 blocks
    IWT_kernel<<<16384, 256, 0, stream>>>(x, out);
}